// Round 12
// baseline (139.546 us; speedup 1.0000x reference)
//
#include <hip/hip_runtime.h>

// NaiveFourierKANLayer: y = cos-features @ W0^T + sin-features @ W1^T + bias
// N=32768, INPUTDIM=64, OUTDIM=256, GRIDSIZE=32 -> GEMM M=32768, N=256, K=4096
//
// R14 changes vs R12 (65.0 us verified; R13's 32x32 retry regressed: write
// conflicts 3x + 4 dependent acc chains -> reverted to R12 structure):
//  - N-split blocks: BN=128, grid (2 n-halves x 512 m) = 4 blocks/CU
//    available. Per-wave acc halves to 4x4 frags = 64 AGPR; breg[4]+af[4]
//    -> ~145 total regs -> __launch_bounds__(256,3) -> 3 waves/SIMD
//    (12 waves/CU, +50% issue streams vs R12's 2-wave starvation).
//    B L2-traffic per CU-kt unchanged (blocks read half of B each).
//  - BK=2 (As dbuf 2x2x8KB = 32KB; union with red[64][132] = 33.8KB/block
//    -> LDS fits 4 blocks). Barrier per 2 kt.
//  - Cost accepted: 2x global feature-trig (VALU stays under the MFMA
//    floor). All per-lane formulas R12-verbatim: feature chain (bit-exact),
//    A XOR-swizzle granules, fragment-major B wconv (+1 n-half bit),
//    rolling breg reload, split-k LDS reduction epilogue.

#define IDIM 64
#define ODIM 256
#define KDIM 4096
#define BM 64

typedef __attribute__((ext_vector_type(8))) unsigned short ushort8_t;
typedef __bf16 bf16x8 __attribute__((ext_vector_type(8)));
typedef float floatx4 __attribute__((ext_vector_type(4)));

__device__ __forceinline__ unsigned short f2bf_rne(float f) {
  unsigned int u = __float_as_uint(f);
  return (unsigned short)((u + 0x7FFFu + ((u >> 16) & 1u)) >> 16);
}

// ---- weight gather+convert: fc(2,256,64,32) fp32 -> Wr fragment-major bf16 ----
// 16B granule t: lane=t&63, nt=(t>>6)&3, wn2=(t>>8)&1, wk=(t>>9)&1,
//   nh=(t>>10)&1, kt=t>>11.
// holds W[o][k] for o = nh*128 + wn2*64 + nt*16 + (lane&15),
//   c = wk, g = (lane>>4)*8 + 1..8, i = kt
__global__ void __launch_bounds__(256) wconv(const float* __restrict__ fc,
                                             unsigned short* __restrict__ Wr) {
  int t = blockIdx.x * 256 + threadIdx.x;  // granule index 0..131071
  int lane = t & 63;
  int nt = (t >> 6) & 3;
  int wn2 = (t >> 8) & 1;
  int wk = (t >> 9) & 1;
  int nh = (t >> 10) & 1;
  int kt = t >> 11;
  int o = nh * 128 + wn2 * 64 + nt * 16 + (lane & 15);
  int g0 = (lane >> 4) * 8;
  const float* src = fc + ((size_t)wk << 19) + o * 2048 + kt * 32 + g0;
  const float4 v0 = *(const float4*)(src);
  const float4 v1 = *(const float4*)(src + 4);
  ushort8_t r;
  r[0] = f2bf_rne(v0.x);
  r[1] = f2bf_rne(v0.y);
  r[2] = f2bf_rne(v0.z);
  r[3] = f2bf_rne(v0.w);
  r[4] = f2bf_rne(v1.x);
  r[5] = f2bf_rne(v1.y);
  r[6] = f2bf_rne(v1.z);
  r[7] = f2bf_rne(v1.w);
  *(ushort8_t*)(Wr + (size_t)t * 8) = r;
}

// ---- fused feature-gen + GEMM ----
__global__ void __launch_bounds__(256, 3) fkan_gemm(const float* __restrict__ X,
                                                    const unsigned short* __restrict__ Wr,
                                                    const float* __restrict__ bias,
                                                    float* __restrict__ out) {
  // union: As dbuf [2][2][4096] ushorts = 32768B | red[64][132] f32 = 33792B
  __shared__ __align__(16) unsigned char smem[33792];
  unsigned short* const AsBase = (unsigned short*)smem;
  float* const red = (float*)smem;

  const int t = threadIdx.x;
  const int wv = t >> 6;    // wave 0..3
  const int ln = t & 63;
  const int lm = ln & 15;
  const int quad = ln >> 4;
  const int wk = wv & 1;    // cos(0)/sin(1) k-half
  const int wn2 = wv >> 1;  // 64-col half of this block's 128 cols
  const int nh = blockIdx.x;          // n-half of the 256 output cols
  const int m0 = blockIdx.y * BM;

  // feature role: 4 threads per row, thread q owns g = 8q+1 .. 8q+8
  const int arow = t >> 2;  // 0..63
  const int q = t & 3;
  const float g0f = (float)(8 * q + 1);

  // A write granules (kt-invariant, XOR-swizzled) — verified R2/R3 formulas
  const int ga_c = arow * 8 + (q ^ (arow & 7));
  const int ga_s = arow * 8 + ((4 + q) ^ (arow & 7));

  // B fragment-major base for this wave's (nh, wk, wn2): per kt 16KB stride
  const unsigned short* const bwave =
      Wr + ((size_t)(nh * 16 + wk * 8 + wn2 * 4) * 64 + ln) * 8;

  floatx4 acc[4][4];
#pragma unroll
  for (int a = 0; a < 4; ++a)
#pragma unroll
    for (int b = 0; b < 4; ++b)
      acc[a][b] = (floatx4){0.0f, 0.0f, 0.0f, 0.0f};

  const float* xptr = X + (size_t)(m0 + arow) * IDIM;

  // ---- A staging: chain-of-8 Fourier recurrence (bit-exact R12 form)
  auto features = [&](float xv, int buf, int j) {
    const float inv2pi = 0.15915494309189535f;
    float u = xv * inv2pi;  // x in revolutions
    float u0 = u * g0f;     // g0*x in revolutions
    float c1 = __builtin_amdgcn_cosf(u);
    float s1 = __builtin_amdgcn_sinf(u);
    float C = __builtin_amdgcn_cosf(u0);
    float S = __builtin_amdgcn_sinf(u0);
    bf16x8 cb, sb;
    cb[0] = (__bf16)C;
    sb[0] = (__bf16)S;
#pragma unroll
    for (int jj = 1; jj < 8; ++jj) {
      float Cn = __builtin_fmaf(C, c1, -(S * s1));
      float Sn = __builtin_fmaf(S, c1, (C * s1));
      C = Cn;
      S = Sn;
      cb[jj] = (__bf16)C;
      sb[jj] = (__bf16)S;
    }
    ushort8_t* As8 = (ushort8_t*)(AsBase + (buf * 2 + j) * 4096);
    As8[ga_c] = __builtin_bit_cast(ushort8_t, cb);
    As8[ga_s] = __builtin_bit_cast(ushort8_t, sb);
  };

  bf16x8 breg[4];  // current kt's 4 B fragments (nt), rolling reload

  // ---- MFMA cluster for one kt: 4 af reads, 16 MFMAs, rolling breg reload
  auto cluster = [&](int buf, int j, int reload_kt, bool do_reload) {
    const ushort8_t* A8 = (const ushort8_t*)(AsBase + (buf * 2 + j) * 4096);
    const int ch = wk * 4 + quad;
    bf16x8 af[4];
#pragma unroll
    for (int mt = 0; mt < 4; ++mt) {
      int r = mt * 16 + lm;
      af[mt] = __builtin_bit_cast(bf16x8, A8[r * 8 + (ch ^ (r & 7))]);
    }
    const unsigned short* bn = bwave + (size_t)reload_kt * 16384;
    __builtin_amdgcn_s_setprio(1);
#pragma unroll
    for (int nt = 0; nt < 4; ++nt) {
#pragma unroll
      for (int mt = 0; mt < 4; ++mt)
        acc[mt][nt] = __builtin_amdgcn_mfma_f32_16x16x32_bf16(
            af[mt], breg[nt], acc[mt][nt], 0, 0, 0);
      // reload breg[nt] right after its last use (WAR-safe in-order)
      if (do_reload)
        breg[nt] = __builtin_bit_cast(bf16x8, *(const ushort8_t*)(bn + nt * 512));
    }
    __builtin_amdgcn_s_setprio(0);
  };

  // ---- pair-iteration: compute kt=2s,2s+1 from As[cur], prefetch features
  //      for kt=2s+2,2s+3 into As[nxt], ONE barrier.
  auto ktpair = [&](int s, int cur, int nxt) {
    int k0 = 2 * s;
    float xn0 = xptr[k0 + 2];
    float xn1 = xptr[k0 + 3];
    cluster(cur, 0, k0 + 1, true);
    features(xn0, nxt, 0);
    cluster(cur, 1, k0 + 2, true);
    features(xn1, nxt, 1);
    __syncthreads();
  };

  // ---- prologue: breg <- B(0); features kt 0,1 -> buf 0
#pragma unroll
  for (int nt = 0; nt < 4; ++nt)
    breg[nt] = __builtin_bit_cast(bf16x8, *(const ushort8_t*)(bwave + nt * 512));
  features(xptr[0], 0, 0);
  features(xptr[1], 0, 1);
  __syncthreads();

  // ---- steady state: 31 pairs (s=0..30), unrolled x2
  for (int s = 0; s < 30; s += 2) {
    ktpair(s, 0, 1);
    ktpair(s + 1, 1, 0);
  }
  ktpair(30, 0, 1);  // computes kt 60,61; prefetches 62,63 -> buf 1

  // ---- tail: kt 62,63 from buf 1
  cluster(1, 0, 63, true);
  cluster(1, 1, 0, false);

  // ---- split-k reduction + store: wk=1 partials via padded LDS scratch ----
  __syncthreads();  // As reads done; red may alias As
  if (wk == 1) {
#pragma unroll
    for (int mt = 0; mt < 4; ++mt)
#pragma unroll
      for (int nt = 0; nt < 4; ++nt) {
        int col = wn2 * 64 + nt * 16 + lm;
#pragma unroll
        for (int idx = 0; idx < 4; ++idx)
          red[(mt * 16 + quad * 4 + idx) * 132 + col] = acc[mt][nt][idx];
      }
  }
  __syncthreads();
  if (wk == 0) {
#pragma unroll
    for (int nt = 0; nt < 4; ++nt) {
      int col = wn2 * 64 + nt * 16 + lm;
      float bv = bias[nh * 128 + col];
#pragma unroll
      for (int mt = 0; mt < 4; ++mt) {
        int rbase = m0 + mt * 16 + quad * 4;
#pragma unroll
        for (int idx = 0; idx < 4; ++idx)
          out[(size_t)(rbase + idx) * ODIM + nh * 128 + col] =
              acc[mt][nt][idx] + red[(mt * 16 + quad * 4 + idx) * 132 + col] + bv;
      }
    }
  }
}

extern "C" void kernel_launch(void* const* d_in, const int* in_sizes, int n_in,
                              void* d_out, int out_size, void* d_ws, size_t ws_size,
                              hipStream_t stream) {
  const float* x = (const float*)d_in[0];
  const float* fc = (const float*)d_in[1];
  const float* bias = (const float*)d_in[2];
  float* out = (float*)d_out;
  unsigned short* Wr = (unsigned short*)d_ws;  // 2 MB of workspace

  hipLaunchKernelGGL(wconv, dim3(512), dim3(256), 0, stream, fc, Wr);
  hipLaunchKernelGGL(fkan_gemm, dim3(2, 512), dim3(256), 0, stream, x, Wr, bias, out);
}

// Round 13
// 128.330 us; speedup vs baseline: 1.0874x; 1.0874x over previous
//
#include <hip/hip_runtime.h>

// NaiveFourierKANLayer: y = cos-features @ W0^T + sin-features @ W1^T + bias
// N=32768, INPUTDIM=64, OUTDIM=256, GRIDSIZE=32 -> GEMM M=32768, N=256, K=4096
//
// R15 = fkan_gemm reverted to R12 VERBATIM (best verified: 65.0 us,
// MfmaUtil 47.6, VALUBusy 32.6) + wconv rewritten as an LDS transpose.
// R14 (N-split, 3 waves/SIMD) regressed to 76.5: the 2x feature replication
// pushed VALUBusy to 41% and doubled write conflicts -- occupancy gained via
// duplicated VALU work loses (same lesson as R10).
// wconv since R9 read fc at 8KB/lane stride (uncoalesced 16B gathers) to
// produce the fragment-major layout. New wconv: one block per kt stages
// fc[c][o][kt][:] into LDS via coalesced 128B-segment reads, then emits
// granules in store order -> perfectly contiguous 16B stores. Same values,
// same layout => bit-identical gemm inputs (absmax must stay 0.015625).

#define IDIM 64
#define ODIM 256
#define KDIM 4096
#define BM 64

typedef __attribute__((ext_vector_type(8))) unsigned short ushort8_t;
typedef __bf16 bf16x8 __attribute__((ext_vector_type(8)));
typedef float floatx4 __attribute__((ext_vector_type(4)));

__device__ __forceinline__ unsigned short f2bf_rne(float f) {
  unsigned int u = __float_as_uint(f);
  return (unsigned short)((u + 0x7FFFu + ((u >> 16) & 1u)) >> 16);
}

// ---- weight gather+convert via LDS transpose ----
// Target layout (R9/R12-verified): 16B granule index G = kt*2048 + gg,
//   gg = bb*512 + j*64 + lane, bb = wk*2 + wn2;
//   holds W[o][k] for o = wn2*128 + j*16 + (lane&15), c = wk,
//   g = (lane>>4)*8 + 0..7, i = kt.
// One block per kt: coalesced fc reads -> LDS -> contiguous Wr stores.
__global__ void __launch_bounds__(256) wconv(const float* __restrict__ fc,
                                             unsigned short* __restrict__ Wr) {
  __shared__ unsigned short Sb[2][256][32];  // Sb[c][o][g], 32 KB
  const int t = threadIdx.x;
  const int kt = blockIdx.x;  // 0..63

  // read phase: 512 (c,o) rows x 32 floats; 8 lanes per row, float4 each.
  // Each 8-lane group reads 128B contiguous.
#pragma unroll
  for (int it = 0; it < 16; ++it) {
    int s = it * 256 + t;
    int r = s >> 3;   // row 0..511
    int p = s & 7;    // float4 slot
    int c = r >> 8;
    int o = r & 255;
    const float4 v =
        *(const float4*)(fc + ((size_t)c << 19) + o * 2048 + kt * 32 + p * 4);
    ushort4 w;
    w.x = f2bf_rne(v.x);
    w.y = f2bf_rne(v.y);
    w.z = f2bf_rne(v.z);
    w.w = f2bf_rne(v.w);
    *(ushort4*)&Sb[c][o][p * 4] = w;  // 8B-aligned ds_write_b64
  }
  __syncthreads();

  // write phase: 2048 granules in store order -> contiguous 16B stores
#pragma unroll
  for (int it = 0; it < 8; ++it) {
    int gg = it * 256 + t;
    int lane = gg & 63;
    int j = (gg >> 6) & 7;
    int bb = gg >> 9;  // 0..3
    int wn2 = bb & 1;
    int wk = (bb >> 1) & 1;
    int o = wn2 * 128 + j * 16 + (lane & 15);
    int g0 = (lane >> 4) * 8;
    ushort8_t v = *(const ushort8_t*)&Sb[wk][o][g0];  // 16B-aligned b128
    *(ushort8_t*)(Wr + ((size_t)kt * 2048 + gg) * 8) = v;
  }
}

// ---- fused feature-gen + GEMM (R12 verbatim) ----
__global__ void __launch_bounds__(256, 2) fkan_gemm(const float* __restrict__ X,
                                                    const unsigned short* __restrict__ Wr,
                                                    const float* __restrict__ bias,
                                                    float* __restrict__ out) {
  // red[64][260] f32 = 66560B; As dbuf 2 x (4 kt x 8KB) = 65536B overlaid.
  // As is dead by the time red is written (barrier-separated).
  __shared__ __align__(16) unsigned char smem[66560];
  unsigned short* const AsBase = (unsigned short*)smem;  // [2][4][4096] ushorts
  float* const red = (float*)smem;

  const int t = threadIdx.x;
  const int wv = t >> 6;    // wave 0..3
  const int ln = t & 63;
  const int lm = ln & 15;
  const int quad = ln >> 4;
  const int wk = wv & 1;    // cos(0)/sin(1) k-half
  const int wn2 = wv >> 1;  // col-half (128 cols)
  const int m0 = blockIdx.x * BM;

  // feature role: 4 threads per row, thread q owns g = 8q+1 .. 8q+8
  const int arow = t >> 2;  // 0..63
  const int q = t & 3;
  const float g0f = (float)(8 * q + 1);

  // A write granules (kt-invariant, XOR-swizzled) — verified R2/R3 formulas
  const int ga_c = arow * 8 + (q ^ (arow & 7));
  const int ga_s = arow * 8 + ((4 + q) ^ (arow & 7));

  // B fragment-major base for this wave's (wk, wn2): per kt an 8KB block
  const unsigned short* const bwave = Wr + (size_t)(wk * 2 + wn2) * 4096 + ln * 8;

  floatx4 acc[4][8];
#pragma unroll
  for (int a = 0; a < 4; ++a)
#pragma unroll
    for (int b = 0; b < 8; ++b)
      acc[a][b] = (floatx4){0.0f, 0.0f, 0.0f, 0.0f};

  const float* xptr = X + (size_t)(m0 + arow) * IDIM;

  // ---- A staging: chain-of-8 Fourier recurrence -> As[buf][j] sub-tile
  auto features = [&](float xv, int buf, int j) {
    const float inv2pi = 0.15915494309189535f;
    float u = xv * inv2pi;  // x in revolutions
    float u0 = u * g0f;     // g0*x in revolutions
    float c1 = __builtin_amdgcn_cosf(u);
    float s1 = __builtin_amdgcn_sinf(u);
    float C = __builtin_amdgcn_cosf(u0);
    float S = __builtin_amdgcn_sinf(u0);
    bf16x8 cb, sb;
    cb[0] = (__bf16)C;
    sb[0] = (__bf16)S;
#pragma unroll
    for (int jj = 1; jj < 8; ++jj) {
      float Cn = __builtin_fmaf(C, c1, -(S * s1));
      float Sn = __builtin_fmaf(S, c1, (C * s1));
      C = Cn;
      S = Sn;
      cb[jj] = (__bf16)C;
      sb[jj] = (__bf16)S;
    }
    ushort8_t* As8 = (ushort8_t*)(AsBase + buf * 16384 + j * 4096);
    As8[ga_c] = __builtin_bit_cast(ushort8_t, cb);
    As8[ga_s] = __builtin_bit_cast(ushort8_t, sb);
  };

  bf16x8 breg[8];  // current kt's B fragments (register-resident)

  // ---- MFMA cluster for one kt: af from As[buf][j]; rolling breg reload
  auto cluster = [&](int buf, int j, int reload_kt, bool do_reload) {
    const ushort8_t* A8 = (const ushort8_t*)(AsBase + buf * 16384 + j * 4096);
    const int ch = wk * 4 + quad;
    bf16x8 af[4];
#pragma unroll
    for (int mt = 0; mt < 4; ++mt) {
      int r = mt * 16 + lm;
      af[mt] = __builtin_bit_cast(bf16x8, A8[r * 8 + (ch ^ (r & 7))]);
    }
    const unsigned short* bn = bwave + (size_t)reload_kt * 16384;
    __builtin_amdgcn_s_setprio(1);
#pragma unroll
    for (int nt = 0; nt < 8; ++nt) {
#pragma unroll
      for (int mt = 0; mt < 4; ++mt)
        acc[mt][nt] = __builtin_amdgcn_mfma_f32_16x16x32_bf16(
            af[mt], breg[nt], acc[mt][nt], 0, 0, 0);
      // reload breg[nt] right after its last use (WAR-safe in-order)
      if (do_reload)
        breg[nt] = __builtin_bit_cast(bf16x8, *(const ushort8_t*)(bn + nt * 512));
    }
    __builtin_amdgcn_s_setprio(0);
  };

  // ---- super-iteration: compute kt=4s..4s+3 from As[cur], prefetch
  //      features for kt=4s+4..4s+7 into As[nxt], ONE barrier.
  auto ktquad = [&](int s, int cur, int nxt) {
    int k0 = 4 * s;
    float xn0 = xptr[k0 + 4];
    float xn1 = xptr[k0 + 5];
    float xn2 = xptr[k0 + 6];
    float xn3 = xptr[k0 + 7];
    cluster(cur, 0, k0 + 1, true);
    features(xn0, nxt, 0);
    cluster(cur, 1, k0 + 2, true);
    features(xn1, nxt, 1);
    cluster(cur, 2, k0 + 3, true);
    features(xn2, nxt, 2);
    cluster(cur, 3, k0 + 4, true);
    features(xn3, nxt, 3);
    __syncthreads();
  };

  // ---- prologue: breg <- B(0); features kt 0..3 -> buf 0
#pragma unroll
  for (int nt = 0; nt < 8; ++nt)
    breg[nt] = __builtin_bit_cast(bf16x8, *(const ushort8_t*)(bwave + nt * 512));
  features(xptr[0], 0, 0);
  features(xptr[1], 0, 1);
  features(xptr[2], 0, 2);
  features(xptr[3], 0, 3);
  __syncthreads();

  // ---- steady state: 15 super-iterations (s=0..14), unrolled x2
  for (int s = 0; s < 14; s += 2) {
    ktquad(s, 0, 1);
    ktquad(s + 1, 1, 0);
  }
  ktquad(14, 0, 1);  // computes kt 56..59, prefetches 60..63 -> buf 1

  // ---- tail: kt 60..63 from buf 1; reloads B(61..63), last no reload
  cluster(1, 0, 61, true);
  cluster(1, 1, 62, true);
  cluster(1, 2, 63, true);
  cluster(1, 3, 0, false);

  // ---- split-k reduction + store: wk=1 partials via padded LDS scratch ----
  __syncthreads();  // As reads done; red may alias As
  if (wk == 1) {
#pragma unroll
    for (int mt = 0; mt < 4; ++mt)
#pragma unroll
      for (int nt = 0; nt < 8; ++nt) {
        int col = wn2 * 128 + nt * 16 + lm;
#pragma unroll
        for (int idx = 0; idx < 4; ++idx)
          red[(mt * 16 + quad * 4 + idx) * 260 + col] = acc[mt][nt][idx];
      }
  }
  __syncthreads();
  if (wk == 0) {
#pragma unroll
    for (int nt = 0; nt < 8; ++nt) {
      int col = wn2 * 128 + nt * 16 + lm;
      float bv = bias[col];
#pragma unroll
      for (int mt = 0; mt < 4; ++mt) {
        int rbase = m0 + mt * 16 + quad * 4;
#pragma unroll
        for (int idx = 0; idx < 4; ++idx)
          out[(size_t)(rbase + idx) * ODIM + col] =
              acc[mt][nt][idx] + red[(mt * 16 + quad * 4 + idx) * 260 + col] + bv;
      }
    }
  }
}

extern "C" void kernel_launch(void* const* d_in, const int* in_sizes, int n_in,
                              void* d_out, int out_size, void* d_ws, size_t ws_size,
                              hipStream_t stream) {
  const float* x = (const float*)d_in[0];
  const float* fc = (const float*)d_in[1];
  const float* bias = (const float*)d_in[2];
  float* out = (float*)d_out;
  unsigned short* Wr = (unsigned short*)d_ws;  // 2 MB of workspace

  hipLaunchKernelGGL(wconv, dim3(64), dim3(256), 0, stream, fc, Wr);
  hipLaunchKernelGGL(fkan_gemm, dim3(512), dim3(256), 0, stream, x, Wr, bias, out);
}

// Round 14
// 127.090 us; speedup vs baseline: 1.0980x; 1.0098x over previous
//
#include <hip/hip_runtime.h>

// NaiveFourierKANLayer: y = cos-features @ W0^T + sin-features @ W1^T + bias
// N=32768, INPUTDIM=64, OUTDIM=256, GRIDSIZE=32 -> GEMM M=32768, N=256, K=4096
//
// R16 changes vs R15 (64.4 us gemm verified; R12 structure + LDS-transpose
// wconv):
//  - Split-k dropped. Waves are n-QUARTERS (64 cols, full K per kt) instead
//    of (k-half x col-half): acc halves to 64 AGPR, and the split-k epilogue
//    (red LDS round-trip + 2 barriers, stores on half the waves) is deleted
//    -- direct stores from all 4 waves. Accumulation order = R13's
//    (verified absmax 0.015625).
//  - af reads double (8 b128/wave-kt, both cos+sin chunks); LDS port has
//    headroom (R9: port not binding). B traffic per CU unchanged (each wave
//    reads its own 64-col slice, 8KB/kt -> 16 TB/s L2 demand, same as R12).
//  - LDS halves to 64KB (As dbuf only). BK=4 cadence, rolling breg reload,
//    bit-exact feature chain, XOR swizzles, wconv: R15-verbatim.

#define IDIM 64
#define ODIM 256
#define KDIM 4096
#define BM 64

typedef __attribute__((ext_vector_type(8))) unsigned short ushort8_t;
typedef __bf16 bf16x8 __attribute__((ext_vector_type(8)));
typedef float floatx4 __attribute__((ext_vector_type(4)));

__device__ __forceinline__ unsigned short f2bf_rne(float f) {
  unsigned int u = __float_as_uint(f);
  return (unsigned short)((u + 0x7FFFu + ((u >> 16) & 1u)) >> 16);
}

// ---- weight gather+convert via LDS transpose (R15-verbatim) ----
// Target layout: 16B granule index G = kt*2048 + gg,
//   gg = bb*512 + j*64 + lane, bb = c*2 + wn2;
//   holds W[o][k] for o = wn2*128 + j*16 + (lane&15),
//   g = (lane>>4)*8 + 0..7, i = kt (k = i*64 + c*32 + g).
__global__ void __launch_bounds__(256) wconv(const float* __restrict__ fc,
                                             unsigned short* __restrict__ Wr) {
  __shared__ unsigned short Sb[2][256][32];  // Sb[c][o][g], 32 KB
  const int t = threadIdx.x;
  const int kt = blockIdx.x;  // 0..63

  // read phase: 512 (c,o) rows x 32 floats; 8 lanes per row, float4 each.
#pragma unroll
  for (int it = 0; it < 16; ++it) {
    int s = it * 256 + t;
    int r = s >> 3;   // row 0..511
    int p = s & 7;    // float4 slot
    int c = r >> 8;
    int o = r & 255;
    const float4 v =
        *(const float4*)(fc + ((size_t)c << 19) + o * 2048 + kt * 32 + p * 4);
    ushort4 w;
    w.x = f2bf_rne(v.x);
    w.y = f2bf_rne(v.y);
    w.z = f2bf_rne(v.z);
    w.w = f2bf_rne(v.w);
    *(ushort4*)&Sb[c][o][p * 4] = w;
  }
  __syncthreads();

  // write phase: 2048 granules in store order -> contiguous 16B stores
#pragma unroll
  for (int it = 0; it < 8; ++it) {
    int gg = it * 256 + t;
    int lane = gg & 63;
    int j = (gg >> 6) & 7;
    int bb = gg >> 9;  // 0..3
    int wn2 = bb & 1;
    int c = (bb >> 1) & 1;
    int o = wn2 * 128 + j * 16 + (lane & 15);
    int g0 = (lane >> 4) * 8;
    ushort8_t v = *(const ushort8_t*)&Sb[c][o][g0];
    *(ushort8_t*)(Wr + ((size_t)kt * 2048 + gg) * 8) = v;
  }
}

// ---- fused feature-gen + GEMM ----
__global__ void __launch_bounds__(256, 2) fkan_gemm(const float* __restrict__ X,
                                                    const unsigned short* __restrict__ Wr,
                                                    const float* __restrict__ bias,
                                                    float* __restrict__ out) {
  // As dbuf: [2 buf][4 kt][4096 ushorts] = 64KB. No reduction scratch.
  __shared__ __align__(16) unsigned short As[2][4][4096];
  unsigned short* const AsBase = &As[0][0][0];

  const int t = threadIdx.x;
  const int wv = t >> 6;  // wave 0..3 = n-quarter
  const int ln = t & 63;
  const int lm = ln & 15;
  const int quad = ln >> 4;
  const int wn = wv;
  const int m0 = blockIdx.x * BM;

  // feature role: 4 threads per row, thread q owns g = 8q+1 .. 8q+8
  const int arow = t >> 2;  // 0..63
  const int q = t & 3;
  const float g0f = (float)(8 * q + 1);

  // A write granules (kt-invariant, XOR-swizzled) — verified R2/R3 formulas
  const int ga_c = arow * 8 + (q ^ (arow & 7));
  const int ga_s = arow * 8 + ((4 + q) ^ (arow & 7));

  // B fragment-major base for this wave's n-quarter:
  //   granule(c, nt) = (c*2 + wn2)*512 + ((wn&1)*4 + nt)*64 + ln
  //   = base(wn2*512 + (wn&1)*256 + ln) + c*1024 + nt*64  [granules]
  const int wn2 = wn >> 1;
  const unsigned short* const bwave =
      Wr + ((size_t)wn2 * 512 + (wn & 1) * 256 + ln) * 8;

  floatx4 acc[4][4];
#pragma unroll
  for (int a = 0; a < 4; ++a)
#pragma unroll
    for (int b = 0; b < 4; ++b)
      acc[a][b] = (floatx4){0.0f, 0.0f, 0.0f, 0.0f};

  const float* xptr = X + (size_t)(m0 + arow) * IDIM;

  // ---- A staging: chain-of-8 Fourier recurrence -> As[buf][j] sub-tile
  auto features = [&](float xv, int buf, int j) {
    const float inv2pi = 0.15915494309189535f;
    float u = xv * inv2pi;  // x in revolutions
    float u0 = u * g0f;     // g0*x in revolutions
    float c1 = __builtin_amdgcn_cosf(u);
    float s1 = __builtin_amdgcn_sinf(u);
    float C = __builtin_amdgcn_cosf(u0);
    float S = __builtin_amdgcn_sinf(u0);
    bf16x8 cb, sb;
    cb[0] = (__bf16)C;
    sb[0] = (__bf16)S;
#pragma unroll
    for (int jj = 1; jj < 8; ++jj) {
      float Cn = __builtin_fmaf(C, c1, -(S * s1));
      float Sn = __builtin_fmaf(S, c1, (C * s1));
      C = Cn;
      S = Sn;
      cb[jj] = (__bf16)C;
      sb[jj] = (__bf16)S;
    }
    ushort8_t* As8 = (ushort8_t*)&As[buf][j][0];
    As8[ga_c] = __builtin_bit_cast(ushort8_t, cb);
    As8[ga_s] = __builtin_bit_cast(ushort8_t, sb);
  };

  bf16x8 breg[8];  // b = c*4 + nt B fragments, register-resident

  // ---- MFMA cluster for one kt: 8 af b128 reads, 32 MFMAs, rolling reload
  auto cluster = [&](int buf, int j, int reload_kt, bool do_reload) {
    const ushort8_t* A8 = (const ushort8_t*)&As[buf][j][0];
    bf16x8 af[8];  // af[c*4 + mt]
#pragma unroll
    for (int c = 0; c < 2; ++c)
#pragma unroll
      for (int mt = 0; mt < 4; ++mt) {
        int r = mt * 16 + lm;
        int ch = c * 4 + quad;
        af[c * 4 + mt] =
            __builtin_bit_cast(bf16x8, A8[r * 8 + (ch ^ (r & 7))]);
      }
    const unsigned short* bn = bwave + (size_t)reload_kt * 16384;
    __builtin_amdgcn_s_setprio(1);
#pragma unroll
    for (int b = 0; b < 8; ++b) {  // b = c*4 + nt
      const int c = b >> 2;
      const int nt = b & 3;
#pragma unroll
      for (int mt = 0; mt < 4; ++mt)
        acc[mt][nt] = __builtin_amdgcn_mfma_f32_16x16x32_bf16(
            af[c * 4 + mt], breg[b], acc[mt][nt], 0, 0, 0);
      // reload breg[b] right after its last use (WAR-safe in-order)
      if (do_reload)
        breg[b] = __builtin_bit_cast(
            bf16x8, *(const ushort8_t*)(bn + (c * 1024 + nt * 64) * 8));
    }
    __builtin_amdgcn_s_setprio(0);
  };

  // ---- super-iteration: compute kt=4s..4s+3 from As[cur], prefetch
  //      features for kt=4s+4..4s+7 into As[nxt], ONE barrier.
  auto ktquad = [&](int s, int cur, int nxt) {
    int k0 = 4 * s;
    float xn0 = xptr[k0 + 4];
    float xn1 = xptr[k0 + 5];
    float xn2 = xptr[k0 + 6];
    float xn3 = xptr[k0 + 7];
    cluster(cur, 0, k0 + 1, true);
    features(xn0, nxt, 0);
    cluster(cur, 1, k0 + 2, true);
    features(xn1, nxt, 1);
    cluster(cur, 2, k0 + 3, true);
    features(xn2, nxt, 2);
    cluster(cur, 3, k0 + 4, true);
    features(xn3, nxt, 3);
    __syncthreads();
  };

  // ---- prologue: breg <- B(0); features kt 0..3 -> buf 0
#pragma unroll
  for (int b = 0; b < 8; ++b)
    breg[b] = __builtin_bit_cast(
        bf16x8,
        *(const ushort8_t*)(bwave + ((b >> 2) * 1024 + (b & 3) * 64) * 8));
  features(xptr[0], 0, 0);
  features(xptr[1], 0, 1);
  features(xptr[2], 0, 2);
  features(xptr[3], 0, 3);
  __syncthreads();

  // ---- steady state: 15 super-iterations (s=0..14), unrolled x2
  for (int s = 0; s < 14; s += 2) {
    ktquad(s, 0, 1);
    ktquad(s + 1, 1, 0);
  }
  ktquad(14, 0, 1);  // computes kt 56..59, prefetches 60..63 -> buf 1

  // ---- tail: kt 60..63 from buf 1; reloads B(61..63), last no reload
  cluster(1, 0, 61, true);
  cluster(1, 1, 62, true);
  cluster(1, 2, 63, true);
  cluster(1, 3, 0, false);

  // ---- epilogue: direct store from all 4 waves (verified C/D map)
#pragma unroll
  for (int nt = 0; nt < 4; ++nt) {
    int col = wn * 64 + nt * 16 + lm;
    float bv = bias[col];
#pragma unroll
    for (int mt = 0; mt < 4; ++mt) {
      int rbase = m0 + mt * 16 + quad * 4;
#pragma unroll
      for (int idx = 0; idx < 4; ++idx)
        out[(size_t)(rbase + idx) * ODIM + col] = acc[mt][nt][idx] + bv;
    }
  }
}

extern "C" void kernel_launch(void* const* d_in, const int* in_sizes, int n_in,
                              void* d_out, int out_size, void* d_ws, size_t ws_size,
                              hipStream_t stream) {
  const float* x = (const float*)d_in[0];
  const float* fc = (const float*)d_in[1];
  const float* bias = (const float*)d_in[2];
  float* out = (float*)d_out;
  unsigned short* Wr = (unsigned short*)d_ws;  // 2 MB of workspace

  hipLaunchKernelGGL(wconv, dim3(64), dim3(256), 0, stream, fc, Wr);
  hipLaunchKernelGGL(fkan_gemm, dim3(512), dim3(256), 0, stream, x, Wr, bias, out);
}